// Round 13
// baseline (1366.307 us; speedup 1.0000x reference)
//
#include <hip/hip_runtime.h>

typedef _Float16 half8 __attribute__((ext_vector_type(8)));
typedef _Float16 f16x2 __attribute__((ext_vector_type(2)));
typedef _Float16 f16x4 __attribute__((ext_vector_type(4)));
typedef float floatx4 __attribute__((ext_vector_type(4)));

#define NB 256    // batch
#define NT 512    // time
#define NI 64     // input
#define NH 256    // hidden
#define NSEQ 16   // sequences per group
#define QB 4      // hidden quarters (blocks per group)
#define NGRP (NB / NSEQ)     // 16 groups
#define NBLK (NGRP * QB)     // 64 blocks, 1 CU each
#define THR 256              // 4 waves
#define HS 344               // H row stride in f16 (validated bank pattern)

// B-fragment pack (VALIDATED R9/R10): 480 frags x 64 lanes x 8 f16.
// Cols: [0,256)=r, [256,512)=z, [512,768)=h_n, [768,1024)=i_n. K: [0,256)=h, [256,320)=x.
// frag f: r: tt*10+kb; z: 160+tt*10+kb; h_n: 320+tt*8+kb (kb<8); i_n: 448+tt*2+(kb-8).
// wb[f*512 + lane*8 + i] = W[k = kb*32 + (lane>>4)*8 + i][n = tt*16 + (lane&15)]
#define WB_N (480 * 512)
#define HD_N ((size_t)NT * NB * NH)
#define HX_N ((size_t)2 * NB * NH)   // parity-double-buffered h exchange (f16)

__global__ __launch_bounds__(256) void gru_prep_kernel(
    const float* __restrict__ w_ih, const float* __restrict__ w_hh,
    _Float16* __restrict__ wb, int* __restrict__ flags)
{
  if (blockIdx.x == 0 && threadIdx.x < NBLK) flags[threadIdx.x * 32] = 0;  // reset (padded)
  int n = blockIdx.x * 256 + threadIdx.x;
  if (n >= WB_N) return;
  int i = n & 7, l = (n >> 3) & 63, f = n >> 9;
  int q = l >> 4, col = l & 15;
  int tt, kb, gate;
  if (f < 160)      { tt = f / 10;               kb = f % 10;        gate = 0; }
  else if (f < 320) { int f2 = f - 160; tt = f2 / 10; kb = f2 % 10;  gate = 1; }
  else if (f < 448) { int f3 = f - 320; tt = f3 / 8;  kb = f3 % 8;   gate = 2; }
  else              { int f4 = f - 448; tt = f4 / 2;  kb = 8 + (f4 & 1); gate = 3; }
  int j = (tt & 15) * 16 + col;
  int k = kb * 32 + q * 8 + i;
  float v;
  if (gate == 0)      v = (k < 256) ? w_hh[(0   + j) * 256 + k] : w_ih[(0   + j) * 64 + (k - 256)];
  else if (gate == 1) v = (k < 256) ? w_hh[(256 + j) * 256 + k] : w_ih[(256 + j) * 64 + (k - 256)];
  else if (gate == 2) v = w_hh[(512 + j) * 256 + k];
  else                v = w_ih[(512 + j) * 64 + (k - 256)];
  wb[n] = (_Float16)v;
}

__device__ __forceinline__ float sigm(float v) {
  return __builtin_amdgcn_rcpf(1.0f + __expf(-v));
}
__device__ __forceinline__ float tanh_f(float v) {
  return 1.0f - 2.0f * __builtin_amdgcn_rcpf(1.0f + __expf(2.0f * v));
}

#define MFMA16(a, b, c) __builtin_amdgcn_mfma_f32_16x16x32_f16(a, b, c, 0, 0, 0)
#define FDOT(W, X, A) __builtin_amdgcn_fdot2(__builtin_bit_cast(f16x2, W), \
                                             __builtin_bit_cast(f16x2, X), A, false)

// Relaxed agent-scope atomics: sc1-flagged, device coherence point (L3-served),
// zero cache-maintenance instructions emitted.
typedef unsigned long long u64;
__device__ __forceinline__ u64 hx_load8(const u64* p) {
  return __hip_atomic_load(p, __ATOMIC_RELAXED, __HIP_MEMORY_SCOPE_AGENT);
}
__device__ __forceinline__ void hx_store8(u64* p, u64 v) {
  __hip_atomic_store(p, v, __ATOMIC_RELAXED, __HIP_MEMORY_SCOPE_AGENT);
}

// ------------- R23: split-K pipeline across the exchange -------------
// R21 measured 5360 cyc/step with a ~3100-cyc exchange chain SERIAL after the
// GEMM. But the GEMM's K decomposes by quarter: own-quarter K-slices (kb=2qb,
// 2qb+1) depend only on LOCALLY produced h cols. R23 reorders:
//   finish GEMM (6 partner kb + 2 x kb) -> GATE -> copy-out (R21's 8B form,
//   R22's 2B fold was the regression) -> vmcnt -> flag STORE (no RMW) ->
//   [overlap: x(t+1) write; waves1-3 poll(LOAD spin)+issue gathers, run own-kb
//   partial GEMM (6 MFMAs) under the gather RTT, write partner cols; wave0 HD
//   dump + partial GEMM] -> barrier. Accumulators carry across iterations.
// Same parity-HX / monotone-flag protocol as R19/R21 (skew<=1 proof unchanged).
// Predicted ~3350 cyc/step -> ~750-880 us.
__global__ __launch_bounds__(THR) void gru_kernel(
    const float* __restrict__ x,      // [B, T, I]
    const float* __restrict__ b_ih,   // [768]
    const float* __restrict__ b_hh,   // [768]
    const _Float16* __restrict__ wb,  // packed B fragments
    _Float16* __restrict__ HD,        // [NT][NB][NH] f16 hidden-state dump
    _Float16* __restrict__ HX,        // [2][NB][NH] f16 h exchange (parity)
    int* __restrict__ flags)          // [NBLK*32] monotone step flags (padded)
{
  __shared__ __align__(16) _Float16 H[2][NSEQ][HS];   // 22016 B, double-buffered
  __shared__ __align__(16) _Float16 WB[120 * 512];    // 122880 B: this block's B-slice

  const int tid  = threadIdx.x;     // 0..255
  const int lane = tid & 63;
  const int w    = tid >> 6;        // wave 0..3
  const int q    = lane >> 4;       // quad 0..3
  const int col  = lane & 15;
  const int gidx = blockIdx.x & 15; // group 0..15  (same-XCD partner mapping)
  const int qb   = blockIdx.x >> 4; // hidden quarter 0..3
  const int b0   = gidx * NSEQ;
  const int tt   = qb * 4 + w;      // global col-tile owned by this wave
  const int j    = tt * 16 + col;   // global hidden unit owned in epilogue

  // ---- stage this block's 120 B-frags to LDS (coalesced float4; validated R19) ----
  {
    const float4* src4 = (const float4*)wb;
    float4* dst4 = (float4*)WB;
    #pragma unroll
    for (int it = 0; it < 30; ++it) {
      int d = tid + it * THR;           // 0..7679
      int slot = d >> 6, elem = d & 63;
      int tau = slot / 30, r = slot % 30;
      int gt = qb * 4 + tau;
      int f = (r < 10) ? (gt * 10 + r)
            : (r < 20) ? (160 + gt * 10 + (r - 10))
            : (r < 28) ? (320 + gt * 8 + (r - 20))
                       : (448 + gt * 2 + (r - 28));
      dst4[d] = src4[(size_t)f * 64 + elem];
    }
  }
  const _Float16* wB = WB + (size_t)(w * 30) * 512 + (size_t)lane * 8;

  const float br   = b_ih[j] + b_hh[j];
  const float bz   = b_ih[256 + j] + b_hh[256 + j];
  const float bin_ = b_ih[512 + j];
  const float bhn  = b_hh[512 + j];

  // ---- init: zero H (both buffers), stage x(t=0) ----
  {
    float4* hz = (float4*)H;
    #pragma unroll
    for (int it = 0; it < 6; ++it) {
      int idx = tid + it * THR;
      if (idx < (int)(sizeof(H) / 16)) hz[idx] = float4{0, 0, 0, 0};
    }
  }
  const int r16 = tid >> 4, c4 = (tid & 15) * 4;
  const float* xbase = x + (size_t)(b0 + r16) * (NT * NI) + c4;
  __syncthreads();
  {
    float4 v = *(const float4*)xbase;   // x at t=0
    f16x4 xh; xh[0] = (_Float16)v.x; xh[1] = (_Float16)v.y;
    xh[2] = (_Float16)v.z; xh[3] = (_Float16)v.w;
    *(f16x4*)&H[0][r16][256 + c4] = xh;
  }
  float h0 = 0.0f, h1 = 0.0f, h2 = 0.0f, h3 = 0.0f;
  // acc carries own-kb partial of h_{t-1} into iter t; primed 0 (h_{-1} = 0)
  floatx4 cR = {0,0,0,0}, cZ = {0,0,0,0}, cN = {0,0,0,0}, cI = {0,0,0,0};
  __syncthreads();

  for (int t = 0; t < NT; ++t) {
    const int cur = t & 1, nxt = cur ^ 1;   // cur = HX parity for h_t
    const bool exch = (t + 1 < NT);

    // ---- x(t+1) prefetch issue (hidden under finish GEMM) ----
    float4 xv = {0, 0, 0, 0};
    if (exch) xv = *(const float4*)(xbase + (size_t)(t + 1) * NI);

    // ---- FINISH GEMM: 6 partner kb + 2 x kb on H[cur] (acc has own-kb already) ----
    const _Float16* hrow = &H[cur][col][q * 8];
    #pragma unroll
    for (int pi = 1; pi <= 3; ++pi) {
      const int p = (qb + pi) & 3;
      #pragma unroll
      for (int d = 0; d < 2; ++d) {
        const int kb = 2 * p + d;
        half8 a = *(const half8*)(hrow + kb * 32);
        cR = MFMA16(a, *(const half8*)(wB + (size_t)(kb)      * 512), cR);
        cZ = MFMA16(a, *(const half8*)(wB + (size_t)(10 + kb) * 512), cZ);
        cN = MFMA16(a, *(const half8*)(wB + (size_t)(20 + kb) * 512), cN);
      }
    }
    { half8 a = *(const half8*)(hrow + 8 * 32);   // x cols [0,32)
      cR = MFMA16(a, *(const half8*)(wB + (size_t)8  * 512), cR);
      cZ = MFMA16(a, *(const half8*)(wB + (size_t)18 * 512), cZ);
      cI = MFMA16(a, *(const half8*)(wB + (size_t)28 * 512), cI); }
    { half8 a = *(const half8*)(hrow + 9 * 32);   // x cols [32,64)
      cR = MFMA16(a, *(const half8*)(wB + (size_t)9  * 512), cR);
      cZ = MFMA16(a, *(const half8*)(wB + (size_t)19 * 512), cZ);
      cI = MFMA16(a, *(const half8*)(wB + (size_t)29 * 512), cI); }

    // ---- GATE -> H[nxt] own cols: lane owns (j, seqs q*4..q*4+3) ----
#define GATE(m, hvar) { \
    float rr = sigm(cR[m] + br); \
    float zz = sigm(cZ[m] + bz); \
    float nn = tanh_f(cI[m] + bin_ + rr * (cN[m] + bhn)); \
    hvar = (1.0f - zz) * nn + zz * hvar; \
    H[nxt][q * 4 + (m)][j] = (_Float16)hvar; }
    GATE(0, h0) GATE(1, h1) GATE(2, h2) GATE(3, h3)
#undef GATE
    __syncthreads();                      // bar1: H[nxt] own cols complete

    if (exch) {
      // ---- copy-out own quarter -> HX[cur] (256 x 8B, R21's proven form) ----
      {
        u64 cov = *(const u64*)&H[nxt][r16][qb * 64 + (tid & 15) * 4];
        hx_store8((u64*)(HX + ((size_t)cur * NB + b0 + r16) * NH + qb * 64 + (tid & 15) * 4), cov);
      }
      asm volatile("s_waitcnt vmcnt(0)" ::: "memory");
      __syncthreads();                    // bar2: all stores acked
      if (tid == 0)
        __hip_atomic_store(&flags[(gidx * QB + qb) * 32], t + 1,
                           __ATOMIC_RELAXED, __HIP_MEMORY_SCOPE_AGENT);

      // ---- x(t+1) -> H[nxt] (own reg; load long since complete) ----
      {
        f16x4 xh; xh[0] = (_Float16)xv.x; xh[1] = (_Float16)xv.y;
        xh[2] = (_Float16)xv.z; xh[3] = (_Float16)xv.w;
        *(f16x4*)&H[nxt][r16][256 + c4] = xh;
      }

      // ---- reset acc; overlap window: partial GEMM vs gather RTT ----
      cR = floatx4{0,0,0,0}; cZ = floatx4{0,0,0,0};
      cN = floatx4{0,0,0,0}; cI = floatx4{0,0,0,0};
      const _Float16* hrow2 = &H[nxt][col][q * 8];

      if (w == 0) {
        // wave 0: HD dump h_{t-1} (own quarter) + partial GEMM
        if (t > 0) {
          #pragma unroll
          for (int e = 0; e < 2; ++e) {
            int el = lane + e * 64;
            int row = el >> 3, c8 = el & 7;
            float4 hv = *(const float4*)&H[cur][row][qb * 64 + c8 * 8];
            *(float4*)(HD + ((size_t)(t - 1) * NB + b0 + row) * NH + qb * 64 + c8 * 8) = hv;
          }
        }
        #pragma unroll
        for (int d = 0; d < 2; ++d) {
          const int kb = 2 * qb + d;
          half8 a = *(const half8*)(hrow2 + kb * 32);
          cR = MFMA16(a, *(const half8*)(wB + (size_t)(kb)      * 512), cR);
          cZ = MFMA16(a, *(const half8*)(wB + (size_t)(10 + kb) * 512), cZ);
          cN = MFMA16(a, *(const half8*)(wB + (size_t)(20 + kb) * 512), cN);
        }
      } else {
        // waves 1-3: poll own partner (LOAD spin), issue gathers, cover the
        // RTT with the partial own-kb GEMM, then land partner cols.
        const int pw = (qb + w) & 3;
        const int* fp = &flags[(gidx * QB + pw) * 32];
        while (__hip_atomic_load(fp, __ATOMIC_RELAXED, __HIP_MEMORY_SCOPE_AGENT) < t + 1) {}
        const u64* hxb = (const u64*)(HX + (size_t)cur * NB * NH);
        int u0 = lane, u1 = lane + 64, u2 = lane + 128, u3 = lane + 192;
        u64 v0 = hx_load8(hxb + (size_t)(b0 + (u0 >> 4)) * (NH / 4) + pw * 16 + (u0 & 15));
        u64 v1 = hx_load8(hxb + (size_t)(b0 + (u1 >> 4)) * (NH / 4) + pw * 16 + (u1 & 15));
        u64 v2 = hx_load8(hxb + (size_t)(b0 + (u2 >> 4)) * (NH / 4) + pw * 16 + (u2 & 15));
        u64 v3 = hx_load8(hxb + (size_t)(b0 + (u3 >> 4)) * (NH / 4) + pw * 16 + (u3 & 15));
        #pragma unroll
        for (int d = 0; d < 2; ++d) {
          const int kb = 2 * qb + d;
          half8 a = *(const half8*)(hrow2 + kb * 32);
          cR = MFMA16(a, *(const half8*)(wB + (size_t)(kb)      * 512), cR);
          cZ = MFMA16(a, *(const half8*)(wB + (size_t)(10 + kb) * 512), cZ);
          cN = MFMA16(a, *(const half8*)(wB + (size_t)(20 + kb) * 512), cN);
        }
        *(u64*)&H[nxt][u0 >> 4][pw * 64 + (u0 & 15) * 4] = v0;
        *(u64*)&H[nxt][u1 >> 4][pw * 64 + (u1 & 15) * 4] = v1;
        *(u64*)&H[nxt][u2 >> 4][pw * 64 + (u2 & 15) * 4] = v2;
        *(u64*)&H[nxt][u3 >> 4][pw * 64 + (u3 & 15) * 4] = v3;
      }
      __syncthreads();                    // bar3: H[nxt] fully assembled
    } else {
      // last step (t = NT-1): dump h_{NT-2}; h_{NT-1} handled after loop
      if (tid < 128) {
        int row = tid >> 3, c8 = tid & 7;
        float4 hv = *(const float4*)&H[cur][row][qb * 64 + c8 * 8];
        *(float4*)(HD + ((size_t)(t - 1) * NB + b0 + row) * NH + qb * 64 + c8 * 8) = hv;
      }
    }
  }

  // ---- final dump: h_{NT-1} lives in H[0] (NT even), own 64 cols ----
  if (tid < 128) {
    int row = tid >> 3, c8 = tid & 7;
    float4 hv = *(const float4*)&H[0][row][qb * 64 + c8 * 8];
    *(float4*)(HD + ((size_t)(NT - 1) * NB + b0 + row) * NH + qb * 64 + c8 * 8) = hv;
  }
}

// ---------------- epilogue: out[t][b] = HD[t][b][:] . w_out + b_out ----------------
__global__ __launch_bounds__(256) void gru_out_kernel(
    const _Float16* __restrict__ HD, const float* __restrict__ w_out,
    const float* __restrict__ b_out, float* __restrict__ out)
{
  __shared__ __align__(16) _Float16 WL[NH];
  int tid = threadIdx.x;
  WL[tid] = (_Float16)w_out[tid];
  __syncthreads();
  int gid = blockIdx.x * 256 + tid;          // gid = t*NB + b
  const float4* hp = (const float4*)(HD + (size_t)gid * NH);
  const float4* wp = (const float4*)WL;
  float acc = 0.0f;
  #pragma unroll
  for (int i = 0; i < NH / 8; ++i) {
    float4 hv = hp[i];
    float4 wv = wp[i];
    acc = FDOT(hv.x, wv.x, acc);
    acc = FDOT(hv.y, wv.y, acc);
    acc = FDOT(hv.z, wv.z, acc);
    acc = FDOT(hv.w, wv.w, acc);
  }
  out[gid] = acc + b_out[0];
}

extern "C" void kernel_launch(void* const* d_in, const int* in_sizes, int n_in,
                              void* d_out, int out_size, void* d_ws, size_t ws_size,
                              hipStream_t stream) {
  const float* x     = (const float*)d_in[0];
  const float* w_ih  = (const float*)d_in[1];
  const float* w_hh  = (const float*)d_in[2];
  const float* b_ih  = (const float*)d_in[3];
  const float* b_hh  = (const float*)d_in[4];
  const float* w_out = (const float*)d_in[5];
  const float* b_out = (const float*)d_in[6];
  float* out = (float*)d_out;

  _Float16* wb = (_Float16*)d_ws;            // 480 KB packed B fragments
  _Float16* HD = wb + WB_N;                  // 64 MB hidden-state dump
  _Float16* HX = HD + HD_N;                  // 256 KB h exchange (parity-buffered)
  int* flags   = (int*)(HX + HX_N);          // 8 KB padded monotone flags

  gru_prep_kernel<<<(WB_N + 255) / 256, 256, 0, stream>>>(w_ih, w_hh, wb, flags);
  gru_kernel<<<NBLK, THR, 0, stream>>>(x, b_ih, b_hh, wb, HD, HX, flags);
  gru_out_kernel<<<(NT * NB) / 256, 256, 0, stream>>>(HD, w_out, b_out, out);
}

// Round 14
// 1034.088 us; speedup vs baseline: 1.3213x; 1.3213x over previous
//
#include <hip/hip_runtime.h>

typedef _Float16 half8 __attribute__((ext_vector_type(8)));
typedef _Float16 f16x2 __attribute__((ext_vector_type(2)));
typedef float floatx4 __attribute__((ext_vector_type(4)));

#define NB 256    // batch
#define NT 512    // time
#define NI 64     // input
#define NH 256    // hidden
#define NSEQ 16   // sequences per block
#define NBLK (NB / NSEQ)   // 16 blocks
#define THR 512            // 8 waves, 2 waves/SIMD
#define HS 344             // H row stride in f16

// B-fragment pack (VALIDATED R9/R10): 480 frags x 64 lanes x 8 f16.
// Cols: [0,256)=r, [256,512)=z, [512,768)=h_n, [768,1024)=i_n. K: [0,256)=h, [256,320)=x.
// frag f: r: tt*10+kb; z: 160+tt*10+kb; h_n: 320+tt*8+kb (kb<8); i_n: 448+tt*2+(kb-8).
// wb[f*512 + lane*8 + i] = W[k = kb*32 + (lane>>4)*8 + i][n = tt*16 + (lane&15)]
#define WB_N (480 * 512)

__global__ __launch_bounds__(256) void gru_prep_kernel(
    const float* __restrict__ w_ih, const float* __restrict__ w_hh,
    _Float16* __restrict__ wb)
{
  int n = blockIdx.x * 256 + threadIdx.x;
  if (n >= WB_N) return;
  int i = n & 7, l = (n >> 3) & 63, f = n >> 9;
  int q = l >> 4, col = l & 15;
  int tt, kb, gate;
  if (f < 160)      { tt = f / 10;               kb = f % 10;        gate = 0; }
  else if (f < 320) { int f2 = f - 160; tt = f2 / 10; kb = f2 % 10;  gate = 1; }
  else if (f < 448) { int f3 = f - 320; tt = f3 / 8;  kb = f3 % 8;   gate = 2; }
  else              { int f4 = f - 448; tt = f4 / 2;  kb = 8 + (f4 & 1); gate = 3; }
  int j = (tt & 15) * 16 + col;
  int k = kb * 32 + q * 8 + i;
  float v;
  if (gate == 0)      v = (k < 256) ? w_hh[(0   + j) * 256 + k] : w_ih[(0   + j) * 64 + (k - 256)];
  else if (gate == 1) v = (k < 256) ? w_hh[(256 + j) * 256 + k] : w_ih[(256 + j) * 64 + (k - 256)];
  else if (gate == 2) v = w_hh[(512 + j) * 256 + k];
  else                v = w_ih[(512 + j) * 64 + (k - 256)];
  wb[n] = (_Float16)v;
}

__device__ __forceinline__ float sigm(float v) {
  return __builtin_amdgcn_rcpf(1.0f + __expf(-v));
}
__device__ __forceinline__ float tanh_f(float v) {
  return 1.0f - 2.0f * __builtin_amdgcn_rcpf(1.0f + __expf(2.0f * v));
}

#define MFMA16(a, b, c) __builtin_amdgcn_mfma_f32_16x16x32_f16(a, b, c, 0, 0, 0)
#define FDOT(W, X, A) __builtin_amdgcn_fdot2(__builtin_bit_cast(f16x2, W), \
                                             __builtin_bit_cast(f16x2, X), A, false)

// ---------------- batched MFMA recurrence: 1 block = 16 sequences ----------------
// R24 = R18 verbatim (measured 1028 us, the session best). Final ledger:
//  - 16-block family floor: B-restream 352 KB/step at the ~64 B/cyc/CU L2-return
//    port (measured invariant 61-65 B/cyc across R10/R11/R12/R18). LDS absorbs
//    128 KB (n-gate); register residency for the rest is compiler-refused
//    (VGPR_Count=128 across 5 pin mechanisms / 8 rounds; gfx950 unified VGPR/AGPR
//    file, R16; occupancy-attr forms, R17/R18).
//  - hidden-split family floor (R19-R23): exchange spine store-drain + flag RTT +
//    poll + gather RTT ~2500-3000 cyc is not coverable (per-step GEMM only ~2000
//    cyc; R23's partial-GEMM cover = 150 cyc vs 700-cyc RTT). Best 1143 (R21).
//  - gi-precompute needs 269 MB workspace (R14 crash); fp8 B halves restream but
//    injects ~2^-3 gate-preact error vs 2^-9 tolerance.
// This config: n-gate frags in LDS (128 KB), r/z pinned-spilled (streams from
// L2-backed scratch at port rate), i_n streamed, single barrier/step.
__global__ __attribute__((amdgpu_flat_work_group_size(THR, THR),
                          amdgpu_waves_per_eu(2, 2)))
void gru_kernel(
    const float* __restrict__ x,      // [B, T, I]
    const float* __restrict__ b_ih,   // [768]
    const float* __restrict__ b_hh,   // [768]
    const _Float16* __restrict__ wb,  // packed B fragments
    _Float16* __restrict__ HD,        // [NT][NB][NH] f16 hidden-state dump
    float* __restrict__ out)          // unused here (kept for symmetry)
{
  __shared__ __align__(16) _Float16 H[2][NSEQ][HS];   // 22016 B, double-buffered
  __shared__ __align__(16) _Float16 WN[128 * 512];    // 131072 B: n-gate frags (16 tiles)

  const int tid  = threadIdx.x;
  const int lane = tid & 63;
  const int w    = tid >> 6;        // wave 0..7
  const int q    = lane >> 4;       // quad 0..3
  const int col  = lane & 15;
  const int b0   = blockIdx.x * NSEQ;
  const int j0   = (2 * w) * 16 + col;      // tile t0 = 2w
  const int j1   = j0 + 16;                 // tile t1 = 2w+1

  const _Float16* wbL = wb + (size_t)lane * 8;

  // ---- stage n-gate frags (wb frags [320,448)) to LDS: 128 KB coalesced ----
  {
    const float4* src = (const float4*)(wb + (size_t)320 * 512);
    float4* dst = (float4*)WN;
    #pragma unroll
    for (int it = 0; it < 16; ++it) dst[tid + it * THR] = src[tid + it * THR];
  }
  // wave's n frags: tile t0 -> frag 16w + k, tile t1 -> frag 16w+8+k
  const _Float16* wnW = WN + (size_t)(16 * w) * 512 + (size_t)lane * 8;

  // ---- persistent B fragments: r + z both tiles (32 x half8 = 128 VGPR) ----
#define LR(T, k) half8 R##T##_##k = *(const half8*)(wbL + (size_t)((2 * w + T) * 10 + (k)) * 512);
  LR(0,0) LR(0,1) LR(0,2) LR(0,3) LR(0,4) LR(0,5) LR(0,6) LR(0,7) LR(0,8) LR(0,9)
  LR(1,0) LR(1,1) LR(1,2) LR(1,3) LR(1,4) LR(1,5) LR(1,6) LR(1,7) LR(1,8) LR(1,9)
#undef LR
#define LZ(T, k) half8 Z##T##_##k = *(const half8*)(wbL + (size_t)(160 + (2 * w + T) * 10 + (k)) * 512);
  LZ(0,0) LZ(0,1) LZ(0,2) LZ(0,3) LZ(0,4) LZ(0,5) LZ(0,6) LZ(0,7) LZ(0,8) LZ(0,9)
  LZ(1,0) LZ(1,1) LZ(1,2) LZ(1,3) LZ(1,4) LZ(1,5) LZ(1,6) LZ(1,7) LZ(1,8) LZ(1,9)
#undef LZ
  // Pin them: asm identity is opaque -> not rematerializable -> must stay in regs.
  asm("" : "+v"(R0_0), "+v"(R0_1), "+v"(R0_2), "+v"(R0_3), "+v"(R0_4),
           "+v"(R0_5), "+v"(R0_6), "+v"(R0_7), "+v"(R0_8), "+v"(R0_9));
  asm("" : "+v"(R1_0), "+v"(R1_1), "+v"(R1_2), "+v"(R1_3), "+v"(R1_4),
           "+v"(R1_5), "+v"(R1_6), "+v"(R1_7), "+v"(R1_8), "+v"(R1_9));
  asm("" : "+v"(Z0_0), "+v"(Z0_1), "+v"(Z0_2), "+v"(Z0_3), "+v"(Z0_4),
           "+v"(Z0_5), "+v"(Z0_6), "+v"(Z0_7), "+v"(Z0_8), "+v"(Z0_9));
  asm("" : "+v"(Z1_0), "+v"(Z1_1), "+v"(Z1_2), "+v"(Z1_3), "+v"(Z1_4),
           "+v"(Z1_5), "+v"(Z1_6), "+v"(Z1_7), "+v"(Z1_8), "+v"(Z1_9));

  // ---- i_n stream pointers (2 frags/tile, re-read from L2 each step; loop-variant) ----
  uintptr_t pI0 = (uintptr_t)(wbL + (size_t)(448 + (2 * w) * 2) * 512);
  uintptr_t pI1 = (uintptr_t)(wbL + (size_t)(448 + (2 * w + 1) * 2) * 512);

  const float br0  = b_ih[j0] + b_hh[j0];
  const float bz0  = b_ih[256 + j0] + b_hh[256 + j0];
  const float bin0 = b_ih[512 + j0];
  const float bhn0 = b_hh[512 + j0];
  const float br1  = b_ih[j1] + b_hh[j1];
  const float bz1  = b_ih[256 + j1] + b_hh[256 + j1];
  const float bin1 = b_ih[512 + j1];
  const float bhn1 = b_hh[512 + j1];

  // ---- init: zero H (both buffers), then x(t=0) into H[0] ----
  {
    float4* hz = (float4*)H;
    #pragma unroll
    for (int it = 0; it < 3; ++it) {
      int idx = tid + it * THR;
      if (idx < (int)(sizeof(H) / 16)) hz[idx] = float4{0, 0, 0, 0};
    }
  }
  __syncthreads();
  H[0][w][256 + lane]     = (_Float16)x[(size_t)(b0 + w)     * (NT * NI) + lane];
  H[0][w + 8][256 + lane] = (_Float16)x[(size_t)(b0 + w + 8) * (NT * NI) + lane];
  float h00 = 0.0f, h01 = 0.0f, h02 = 0.0f, h03 = 0.0f;
  float h10 = 0.0f, h11 = 0.0f, h12 = 0.0f, h13 = 0.0f;
  const float* xp0 = x + (size_t)(b0 + w)     * (NT * NI) + 64 + lane;
  const float* xp1 = x + (size_t)(b0 + w + 8) * (NT * NI) + 64 + lane;
  __syncthreads();

  for (int t = 0; t < NT; ++t) {
    const int cur = t & 1, nxt = cur ^ 1;
    // keep i-stream loads loop-variant (no LICM hoist -> no extra persistent regs)
    asm("" : "+v"(pI0), "+v"(pI1));
    const half8* sI0 = (const half8*)pI0;
    const half8* sI1 = (const half8*)pI1;

    float xv0 = 0.0f, xv1 = 0.0f;
    if (t + 1 < NT) { xv0 = xp0[(size_t)t * 64]; xv1 = xp1[(size_t)t * 64]; }

    // ---- dump h_{t-1} (h-part of H[cur]) to HD[t-1]: all 512 threads ----
    if (t > 0) {
      int row = tid >> 5, ch = tid & 31;
      float4 hv = *(const float4*)&H[cur][row][ch * 8];
      *(float4*)(HD + ((size_t)(t - 1) * NB + b0 + row) * NH + ch * 8) = hv;
    }

    // ---- GEMM: A row = seq = col (validated), 60 MFMAs/wave ----
    const _Float16* hrow = &H[cur][col][q * 8];
    floatx4 cR0 = {0,0,0,0}, cZ0 = {0,0,0,0}, cN0 = {0,0,0,0}, cI0 = {0,0,0,0};
    floatx4 cR1 = {0,0,0,0}, cZ1 = {0,0,0,0}, cN1 = {0,0,0,0}, cI1 = {0,0,0,0};
#define KGRP(k) { \
    half8 a  = *(const half8*)(hrow + (k) * 32); \
    half8 n0 = *(const half8*)(wnW + (size_t)(k) * 512); \
    half8 n1 = *(const half8*)(wnW + (size_t)(8 + (k)) * 512); \
    cR0 = MFMA16(a, R0_##k, cR0); cR1 = MFMA16(a, R1_##k, cR1); \
    cZ0 = MFMA16(a, Z0_##k, cZ0); cZ1 = MFMA16(a, Z1_##k, cZ1); \
    cN0 = MFMA16(a, n0, cN0);     cN1 = MFMA16(a, n1, cN1); }
    KGRP(0) KGRP(1) KGRP(2) KGRP(3) KGRP(4)
    half8 ia0 = sI0[0], ib0 = sI1[0];      // frag kb=8 (used at k=8)
    KGRP(5)
    half8 ia1 = sI0[64], ib1 = sI1[64];    // frag kb=9 (used at k=9)
    KGRP(6) KGRP(7)
#undef KGRP
    { half8 a = *(const half8*)(hrow + 8 * 32);
      cR0 = MFMA16(a, R0_8, cR0); cR1 = MFMA16(a, R1_8, cR1);
      cZ0 = MFMA16(a, Z0_8, cZ0); cZ1 = MFMA16(a, Z1_8, cZ1);
      cI0 = MFMA16(a, ia0, cI0);  cI1 = MFMA16(a, ib0, cI1); }
    { half8 a = *(const half8*)(hrow + 9 * 32);
      cR0 = MFMA16(a, R0_9, cR0); cR1 = MFMA16(a, R1_9, cR1);
      cZ0 = MFMA16(a, Z0_9, cZ0); cZ1 = MFMA16(a, Z1_9, cZ1);
      cI0 = MFMA16(a, ia1, cI0);  cI1 = MFMA16(a, ib1, cI1); }

    // ---- in-register epilogue: lane owns (j0,j1) x (seqs q*4..q*4+3) ----
#define GATE(m, hvar, CR, CZ, CN, CI, BR_, BZ_, BI_, BH_, J) { \
    float rr = sigm(CR[m] + BR_); \
    float zz = sigm(CZ[m] + BZ_); \
    float nn = tanh_f(CI[m] + BI_ + rr * (CN[m] + BH_)); \
    hvar = (1.0f - zz) * nn + zz * hvar; \
    H[nxt][q * 4 + (m)][J] = (_Float16)hvar; }
    GATE(0, h00, cR0, cZ0, cN0, cI0, br0, bz0, bin0, bhn0, j0)
    GATE(1, h01, cR0, cZ0, cN0, cI0, br0, bz0, bin0, bhn0, j0)
    GATE(2, h02, cR0, cZ0, cN0, cI0, br0, bz0, bin0, bhn0, j0)
    GATE(3, h03, cR0, cZ0, cN0, cI0, br0, bz0, bin0, bhn0, j0)
    GATE(0, h10, cR1, cZ1, cN1, cI1, br1, bz1, bin1, bhn1, j1)
    GATE(1, h11, cR1, cZ1, cN1, cI1, br1, bz1, bin1, bhn1, j1)
    GATE(2, h12, cR1, cZ1, cN1, cI1, br1, bz1, bin1, bhn1, j1)
    GATE(3, h13, cR1, cZ1, cN1, cI1, br1, bz1, bin1, bhn1, j1)
#undef GATE
    if (t + 1 < NT) {
      H[nxt][w][256 + lane]     = (_Float16)xv0;
      H[nxt][w + 8][256 + lane] = (_Float16)xv1;
    }

    __syncthreads();   // the single per-step barrier
  }

  // ---- final dump: h_{NT-1} lives in H[0] (NT even) ----
  {
    int row = tid >> 5, ch = tid & 31;
    float4 hv = *(const float4*)&H[0][row][ch * 8];
    *(float4*)(HD + ((size_t)(NT - 1) * NB + b0 + row) * NH + ch * 8) = hv;
  }
}

// ---------------- epilogue: out[t][b] = HD[t][b][:] . w_out + b_out ----------------
__global__ __launch_bounds__(256) void gru_out_kernel(
    const _Float16* __restrict__ HD, const float* __restrict__ w_out,
    const float* __restrict__ b_out, float* __restrict__ out)
{
  __shared__ __align__(16) _Float16 WL[NH];
  int tid = threadIdx.x;
  WL[tid] = (_Float16)w_out[tid];
  __syncthreads();
  int gid = blockIdx.x * 256 + tid;          // gid = t*NB + b
  const float4* hp = (const float4*)(HD + (size_t)gid * NH);
  const float4* wp = (const float4*)WL;
  float acc = 0.0f;
  #pragma unroll
  for (int i = 0; i < NH / 8; ++i) {
    float4 hv = hp[i];
    float4 wv = wp[i];
    acc = FDOT(hv.x, wv.x, acc);
    acc = FDOT(hv.y, wv.y, acc);
    acc = FDOT(hv.z, wv.z, acc);
    acc = FDOT(hv.w, wv.w, acc);
  }
  out[gid] = acc + b_out[0];
}

extern "C" void kernel_launch(void* const* d_in, const int* in_sizes, int n_in,
                              void* d_out, int out_size, void* d_ws, size_t ws_size,
                              hipStream_t stream) {
  const float* x     = (const float*)d_in[0];
  const float* w_ih  = (const float*)d_in[1];
  const float* w_hh  = (const float*)d_in[2];
  const float* b_ih  = (const float*)d_in[3];
  const float* b_hh  = (const float*)d_in[4];
  const float* w_out = (const float*)d_in[5];
  const float* b_out = (const float*)d_in[6];
  float* out = (float*)d_out;

  _Float16* wb = (_Float16*)d_ws;            // 480 KB packed B fragments
  _Float16* HD = wb + WB_N;                  // 64 MB hidden-state dump (16B-aligned)

  gru_prep_kernel<<<(WB_N + 255) / 256, 256, 0, stream>>>(w_ih, w_hh, wb);
  gru_kernel<<<NBLK, THR, 0, stream>>>(x, b_ih, b_hh, wb, HD, out);
  gru_out_kernel<<<(NT * NB) / 256, 256, 0, stream>>>(HD, w_out, b_out, out);
}